// Round 6
// baseline (391.405 us; speedup 1.0000x reference)
//
#include <hip/hip_runtime.h>
#include <hip/hip_bf16.h>
#include <math.h>

#define BB 8
#define NN 4096
#define KNN 20
#define CH 64
#define SAMPLES (BB*NN*KNN)   /* 655360 */
#define EPSF 1e-5f
#define SLOPE 0.2f

/* decode order-preserving uint back to float */
__device__ __forceinline__ float key_decode(unsigned e) {
    return __uint_as_float((e & 0x80000000u) ? (e ^ 0x80000000u) : ~e);
}

/* rank-select flush: merge ovf[0..cnt) + inc[0..19] -> new exact top-20 in inc.
   Latency-flat: 64 independent broadcast ds_reads (no dependent shuffle chain).
   All LDS deps are same-wave (HW in-order DS); wave_barrier pins compiler order. */
__device__ __forceinline__ void rank_flush(unsigned long long* ovf,
                                           unsigned long long* inc,
                                           unsigned long long* scr,
                                           int& cnt, float& kthd, int lane) {
    while (cnt > 0) {
        int take = cnt < 44 ? cnt : 44;
        unsigned long long key;
        if (lane < take)      key = ovf[cnt - take + lane];
        else if (lane >= 44)  key = inc[lane - 44];
        else                  key = ~0ull;
        scr[lane] = key;
        __builtin_amdgcn_wave_barrier();
        int r = 0;
#pragma unroll
        for (int t = 0; t < 64; ++t) {
            unsigned long long kt = scr[t];       /* uniform addr -> broadcast */
            r += (kt < key) ? 1 : 0;
        }
        __builtin_amdgcn_wave_barrier();
        if (r < KNN) inc[r] = key;                /* padding: r >= take+20 > 19 */
        __builtin_amdgcn_wave_barrier();
        kthd = key_decode((unsigned)(inc[KNN-1] >> 32));
        cnt -= take;
    }
}

/* ---------------- K0: precompute (x,y,z,sq) per point (exact ref op order) ----- */
__global__ void pts4_kernel(const float* __restrict__ x, float4* __restrict__ pts4) {
#pragma clang fp contract(off)
    int t = blockIdx.x * 256 + threadIdx.x;       /* 32768 points */
    int b = t >> 12;
    int n = t & (NN - 1);
    const float* xb = x + (size_t)b * 3 * NN;
    float mx = xb[n], my = xb[NN + n], mz = xb[2*NN + n];
    float sq = mx*mx; sq += my*my; sq += mz*mz;   /* ref summation order */
    pts4[t] = make_float4(mx, my, mz, sq);
}

/* ---------------- K1: exact KNN. One wave/query; tiled candidates; rank-select.
   LDS = 2x8KB tile double-buffer + 14KB wave bufs = 30KB -> 32 waves/CU. ------- */
__global__ __launch_bounds__(512) void knn_kernel(const float4* __restrict__ pts4,
                                                  int* __restrict__ idx_out) {
#pragma clang fp contract(off)
    __shared__ float4 T[2][512];                             /* 16 KB */
    __shared__ unsigned long long wb[8][224];                /* 14 KB */
    const int tid = threadIdx.x;
    const int lane = tid & 63;
    const int wv = __builtin_amdgcn_readfirstlane(tid >> 6);
    const int q = blockIdx.x * 8 + wv;                       /* one query/wave */
    const int b = q >> 12;
    const int n = q & (NN - 1);
    const float4* base = pts4 + ((size_t)b << 12);

    float4 stage = base[tid];                                /* tile 0 */
    T[0][tid] = stage;
    const float4 Q = base[n];                                /* Q.w = sqn */
    __syncthreads();

    unsigned long long* ovf = &wb[wv][0];                    /* 0..127  overflow  */
    unsigned long long* inc = &wb[wv][128];                  /* 128..147 top-20   */
    unsigned long long* scr = &wb[wv][160];                  /* 160..223 scratch  */

    float kthd = 0.f;
    int cnt = 0;

    for (int t = 0; t < 8; ++t) {
        if (t < 7) stage = base[((t + 1) << 9) + tid];       /* prefetch next tile */
        const float4* Tc = T[t & 1];
        for (int it = 0; it < 8; ++it) {
            if (cnt > 64) rank_flush(ovf, inc, scr, cnt, kthd, lane);
            const int ml = (it << 6) | lane;
            const int m = (t << 9) | ml;
            const float4 P = Tc[ml];
            float inner = Q.x*P.x; inner += Q.y*P.y; inner += Q.z*P.z;
            const float d = (Q.w - 2.0f*inner) + P.w;        /* bitwise same as R5 */
            if (t == 0 && it == 0) {
                /* prefill: rank-select the first 64 candidates directly */
                unsigned uu = __float_as_uint(d);
                unsigned e = uu ^ (((unsigned)((int)uu >> 31)) | 0x80000000u);
                unsigned long long key = ((unsigned long long)e << 32) | (unsigned)m;
                scr[lane] = key;
                __builtin_amdgcn_wave_barrier();
                int r = 0;
#pragma unroll
                for (int tt = 0; tt < 64; ++tt) {
                    unsigned long long kt = scr[tt];
                    r += (kt < key) ? 1 : 0;
                }
                __builtin_amdgcn_wave_barrier();
                if (r < KNN) inc[r] = key;
                __builtin_amdgcn_wave_barrier();
                kthd = key_decode((unsigned)(inc[KNN-1] >> 32));
            } else {
                bool push = d <= kthd;                       /* <=: keep exact ties */
                unsigned long long mask = __ballot(push);
                if (mask) {
                    if (push) {
                        unsigned uu = __float_as_uint(d);
                        unsigned e = uu ^ (((unsigned)((int)uu >> 31)) | 0x80000000u);
                        unsigned long long key = ((unsigned long long)e << 32) | (unsigned)m;
                        int ofs = (int)__popcll(mask & ((1ull << lane) - 1ull));
                        ovf[cnt + ofs] = key;
                    }
                    cnt += (int)__popcll(mask);
                }
            }
        }
        if (t < 7) T[(t + 1) & 1][tid] = stage;              /* publish next tile */
        __syncthreads();
    }
    rank_flush(ovf, inc, scr, cnt, kthd, lane);
    if (lane < KNN)
        idx_out[(size_t)q * KNN + lane] = (int)(unsigned)(inc[lane] & 0xFFFFFFFFull);
}

/* ---------------- K2: per-point projections u,v ------------------------------- */
__global__ void uv_kernel(const float* __restrict__ x, const float* __restrict__ W1,
                          float* __restrict__ u, float* __restrict__ v) {
    int t = blockIdx.x * 256 + threadIdx.x;       /* t = ((b*N+n)<<6)+o */
    int o = t & 63;
    int n = (t >> 6) & (NN - 1);
    int b = t >> 18;
    float X = x[(b*3 + 0)*NN + n];
    float Y = x[(b*3 + 1)*NN + n];
    float Z = x[(b*3 + 2)*NN + n];
    float w0 = W1[o*6+0], w1 = W1[o*6+1], w2 = W1[o*6+2];
    float w3 = W1[o*6+3], w4 = W1[o*6+4], w5 = W1[o*6+5];
    u[t] = w0*X + w1*Y + w2*Z;
    v[t] = (w3 - w0)*X + (w4 - w1)*Y + (w5 - w2)*Z;
}

/* ---------------- K3: bn1 sums. lane=channel, wave = 4 points ------------------ */
__global__ __launch_bounds__(256, 4) void stats1_kernel(const int* __restrict__ idxb,
        const float* __restrict__ u, const float* __restrict__ v,
        double* __restrict__ stats) {
    __shared__ float rsum[4][64], rsq[4][64];
    const int tid = threadIdx.x;
    const int lane = tid & 63;
    const int wv = __builtin_amdgcn_readfirstlane(tid >> 6);
    float s = 0.f, q = 0.f;
    const int pt0 = (blockIdx.x * 4 + wv) * 4;    /* 4 points per wave */
    const int b = pt0 >> 12;
    for (int p = 0; p < 4; ++p) {
        const int pt = pt0 + p;
        const float vc = v[((size_t)pt << 6) + lane];
        const int* irow = idxb + (size_t)pt * KNN;
        for (int k = 0; k < KNN; ++k) {
            int nbr = irow[k];
            float h = u[(((size_t)(b << 12) + nbr) << 6) + lane] + vc;
            s += h; q = fmaf(h, h, q);
        }
    }
    rsum[wv][lane] = s; rsq[wv][lane] = q;
    __syncthreads();
    if (tid < 64) {
        float ts = rsum[0][lane]+rsum[1][lane]+rsum[2][lane]+rsum[3][lane];
        float tq = rsq[0][lane]+rsq[1][lane]+rsq[2][lane]+rsq[3][lane];
        atomicAdd(&stats[lane], (double)ts);
        atomicAdd(&stats[64 + lane], (double)tq);
    }
}

/* ---------------- K4/K6: finalize bn -> affine a,b ---------------------------- */
__global__ void fin_kernel(const double* __restrict__ stats, const float* __restrict__ gamma,
                           const float* __restrict__ beta, float* __restrict__ ab) {
    int o = threadIdx.x;
    double cnt = (double)SAMPLES;
    double mean = stats[o] / cnt;
    double var  = stats[64 + o] / cnt - mean*mean;
    float a = (float)((double)gamma[o] / sqrt(var + (double)EPSF));
    ab[o] = a;
    ab[64 + o] = beta[o] - a * (float)mean;
}

/* ---------------- K5: main pass. lane=channel o; W2 row in regs; g via LDS ----- */
__global__ __launch_bounds__(256, 4) void main_kernel(const int* __restrict__ idxb,
        const float* __restrict__ u, const float* __restrict__ v,
        const float* __restrict__ ab1, const float* __restrict__ W2,
        float* __restrict__ maxbuf, double* __restrict__ stats2) {
    __shared__ float w2s[64*65];                  /* padded: conflict-free row reads */
    __shared__ float gbuf[4][64];
    __shared__ float rsum[4][64], rsq[4][64];
    const int tid = threadIdx.x;
    const int lane = tid & 63;
    const int wv = __builtin_amdgcn_readfirstlane(tid >> 6);
    for (int i = tid; i < 4096; i += 256)
        w2s[(i >> 6)*65 + (i & 63)] = W2[i];
    __syncthreads();
    float w[64];
#pragma unroll
    for (int c = 0; c < 64; ++c) w[c] = w2s[lane*65 + c];
    const float a1 = ab1[lane], b1 = ab1[64 + lane];
    float ssum = 0.f, ssq = 0.f;
    const float4* gp = (const float4*)&gbuf[wv][0];

    const int pt0 = (blockIdx.x * 4 + wv) * 4;    /* 4 points per wave */
    const int b = pt0 >> 12;
    for (int p = 0; p < 4; ++p) {
        const int pt = pt0 + p;
        const float vc = v[((size_t)pt << 6) + lane];
        const int* irow = idxb + (size_t)pt * KNN;
        float pmax = -3.4e38f;
        for (int k = 0; k < KNN; ++k) {
            int nbr = irow[k];                    /* uniform -> s_load */
            float uc = u[(((size_t)(b << 12) + nbr) << 6) + lane];
            float g = a1 * (uc + vc) + b1;
            g = fmaxf(g, SLOPE * g);              /* leaky-relu, slope<1 */
            gbuf[wv][lane] = g;
            float h = 0.f;
#pragma unroll
            for (int c4 = 0; c4 < 16; ++c4) {
                float4 g4 = gp[c4];               /* uniform-address broadcast */
                h = fmaf(g4.x, w[c4*4+0], h);
                h = fmaf(g4.y, w[c4*4+1], h);
                h = fmaf(g4.z, w[c4*4+2], h);
                h = fmaf(g4.w, w[c4*4+3], h);
            }
            pmax = fmaxf(pmax, h);
            ssum += h;
            ssq = fmaf(h, h, ssq);
        }
        maxbuf[((size_t)pt << 6) + lane] = pmax;  /* (b,n,o) coalesced */
    }
    rsum[wv][lane] = ssum; rsq[wv][lane] = ssq;
    __syncthreads();
    if (tid < 64) {
        float ts = rsum[0][lane]+rsum[1][lane]+rsum[2][lane]+rsum[3][lane];
        float tq = rsq[0][lane]+rsq[1][lane]+rsq[2][lane]+rsq[3][lane];
        atomicAdd(&stats2[lane], (double)ts);
        atomicAdd(&stats2[64 + lane], (double)tq);
    }
}

/* ---------------- K7: epilogue — transpose (b,n,o)->(b,o,n) + bn2 + lrelu ------ */
__global__ __launch_bounds__(256) void out_kernel(const float* __restrict__ maxbuf,
        const float* __restrict__ ab2, float* __restrict__ out) {
    __shared__ float t[64][65];
    const int tid = threadIdx.x;
    const int b = blockIdx.x >> 6;
    const int n0 = (blockIdx.x & 63) << 6;
#pragma unroll
    for (int i = 0; i < 16; ++i) {
        int r = (tid >> 6) + i*4;                 /* n-row */
        int c = tid & 63;                         /* channel */
        t[r][c] = maxbuf[(((size_t)((b << 12) + n0 + r)) << 6) + c];
    }
    __syncthreads();
#pragma unroll
    for (int i = 0; i < 16; ++i) {
        int o = (tid >> 6) + i*4;
        int nn = tid & 63;
        float a = ab2[o], bb = ab2[64 + o];
        float h = a * t[nn][o] + bb;
        out[(((size_t)(b*64 + o)) << 12) + n0 + nn] = h >= 0.f ? h : SLOPE*h;
    }
}

extern "C" void kernel_launch(void* const* d_in, const int* in_sizes, int n_in,
                              void* d_out, int out_size, void* d_ws, size_t ws_size,
                              hipStream_t stream) {
    const float* x      = (const float*)d_in[0];
    const float* W1     = (const float*)d_in[1];
    const float* gamma1 = (const float*)d_in[2];
    const float* beta1  = (const float*)d_in[3];
    const float* W2     = (const float*)d_in[4];
    const float* gamma2 = (const float*)d_in[5];
    const float* beta2  = (const float*)d_in[6];
    float* out = (float*)d_out;

    char* ws = (char*)d_ws;
    int*    idxb   = (int*)   (ws + 0);           /* 2,621,440 B */
    float*  u      = (float*) (ws + 2621440);     /* 8,388,608 B */
    float*  v      = (float*) (ws + 11010048);    /* 8,388,608 B */
    float*  maxbuf = (float*) (ws + 19398656);    /* 8,388,608 B, layout (b,n,o) */
    float4* pts4   = (float4*)(ws + 19398656);    /* 512 KB, aliases maxbuf:
                                                     dead before main_kernel writes */
    double* stats1 = (double*)(ws + 27787264);    /* 1 KB */
    double* stats2 = (double*)(ws + 27788288);    /* 1 KB */
    float*  ab1    = (float*) (ws + 27789312);    /* 512 B */
    float*  ab2    = (float*) (ws + 27789824);    /* 512 B */

    hipMemsetAsync(stats1, 0, 2048, stream);      /* zero stats1+stats2 */

    pts4_kernel  <<<128, 256, 0, stream>>>(x, pts4);
    knn_kernel   <<<4096, 512, 0, stream>>>(pts4, idxb);
    uv_kernel    <<<8192, 256, 0, stream>>>(x, W1, u, v);
    stats1_kernel<<<2048, 256, 0, stream>>>(idxb, u, v, stats1);
    fin_kernel   <<<1, 64, 0, stream>>>(stats1, gamma1, beta1, ab1);
    main_kernel  <<<2048, 256, 0, stream>>>(idxb, u, v, ab1, W2, maxbuf, stats2);
    fin_kernel   <<<1, 64, 0, stream>>>(stats2, gamma2, beta2, ab2);
    out_kernel   <<<512, 256, 0, stream>>>(maxbuf, ab2, out);
}